// Round 1
// baseline (136.460 us; speedup 1.0000x reference)
//
#include <hip/hip_runtime.h>
#include <hip/hip_bf16.h>
#include <math.h>

// Problem constants (from setup_inputs): B=16, H=W=512, P=128, T=64
#define BB   16
#define HH   512
#define WW   512
#define PP   128
#define TT   64

#define TILE_W 64
#define TILE_H 4

__global__ __launch_bounds__(256)
void PatchTransformer_43490838840065_kernel(const float* __restrict__ patch,
                                            const float* __restrict__ targets,
                                            const float* __restrict__ angles,
                                            const float* __restrict__ seeds,
                                            float* __restrict__ out) {
    // ---- tile decode ----
    const int tilesX = WW / TILE_W;           // 8
    const int tilesY = HH / TILE_H;           // 128
    const int tilesPerImg = tilesX * tilesY;  // 1024
    int bid = blockIdx.x;
    int img = bid / tilesPerImg;
    int tr  = bid % tilesPerImg;
    int ty  = tr / tilesX;
    int tx  = tr % tilesX;
    int x0t = tx * TILE_W;
    int y0t = ty * TILE_H;

    // ---- per-target params + tile culling ----
    __shared__ float s_cx[TT], s_cy[TT], s_c[TT], s_s[TT], s_scale[TT], s_add[TT];
    __shared__ int   s_list[TT];
    __shared__ int   s_cnt;

    int tid = threadIdx.x;
    if (tid == 0) s_cnt = 0;
    __syncthreads();

    if (tid < TT) {
        int   ib = (int)targets[tid * 6 + 0];
        float cx = targets[tid * 6 + 2] * (float)WW;
        float ps = targets[tid * 6 + 5] * (float)HH * 0.2f;   // RATIO_H
        float th = angles[tid] * 0.017453292519943295f;       // deg->rad
        float c  = cosf(th);
        float s  = sinf(th);
        float asum = fabsf(c) + fabsf(s);
        float ext  = ps * asum;                               // rotated bbox side
        float cy   = targets[tid * 6 + 3] * (float)HH - 0.2f * ext;
        float scale = (float)(PP - 1) / fmaxf(ps - 1.0f, 1.0f);
        s_cx[tid] = cx;  s_cy[tid] = cy;
        s_c[tid]  = c;   s_s[tid]  = s;
        s_scale[tid] = scale;
        s_add[tid]   = 0.1f * seeds[tid];                     // TEMP_FACTOR * seed

        // footprint: any-tap-in-bounds <=> px,py in [-1, P). In u/v space that's
        // |u|,|v| <= 65/scale. Axis-aligned bbox radius R = r*(|c|+|s|). +1 margin.
        float r = 65.0f / scale + 1.0f;
        float R = r * asum;
        bool hit = (ib == img) &&
                   (cx + R >= (float)x0t) && (cx - R <= (float)(x0t + TILE_W - 1)) &&
                   (cy + R >= (float)y0t) && (cy - R <= (float)(y0t + TILE_H - 1));
        if (hit) {
            int slot = atomicAdd(&s_cnt, 1);
            s_list[slot] = tid;
        }
    }
    __syncthreads();

    // ---- per-pixel accumulate ----
    int lx = tid & (TILE_W - 1);
    int ly = tid / TILE_W;
    int x  = x0t + lx;
    int y  = y0t + ly;
    float fxp = (float)x;
    float fyp = (float)y;

    float val = 0.0f, cov = 0.0f;
    int n = s_cnt;
    for (int k = 0; k < n; ++k) {
        int t = s_list[k];
        float dx = fxp - s_cx[t];
        float dy = fyp - s_cy[t];
        float c  = s_c[t], s = s_s[t];
        float u  =  c * dx + s * dy;
        float v  = -s * dx + c * dy;
        float sc = s_scale[t];
        float px = u * sc + 63.5f;   // half = (P-1)/2
        float py = v * sc + 63.5f;
        float fx0 = floorf(px), fy0 = floorf(py);
        int ix0 = (int)fx0, iy0 = (int)fy0;
        float wx = px - fx0, wy = py - fy0;
        float add = s_add[t];

        #pragma unroll
        for (int dyy = 0; dyy <= 1; ++dyy) {
            #pragma unroll
            for (int dxx = 0; dxx <= 1; ++dxx) {
                int iy = iy0 + dyy;
                int ix = ix0 + dxx;
                bool ok = (iy >= 0) & (iy < PP) & (ix >= 0) & (ix < PP);
                float w = (dyy ? wy : 1.0f - wy) * (dxx ? wx : 1.0f - wx);
                if (ok) {
                    float pv = patch[iy * PP + ix] + add;
                    pv = fminf(fmaxf(pv, 0.0f), 1.0f);        // clip(p0+temp,0,1)
                    val += pv * w;
                    cov += w;
                }
            }
        }
    }

    // ---- write: val -> 3 channels of patch_tf, cov -> 3 channels of mask_tf ----
    size_t plane    = (size_t)HH * WW;
    size_t base0    = ((size_t)img * 3) * plane + (size_t)y * WW + x;
    size_t half_out = (size_t)BB * 3 * plane;
    out[base0]             = val;
    out[base0 + plane]     = val;
    out[base0 + 2 * plane] = val;
    out[half_out + base0]             = cov;
    out[half_out + base0 + plane]     = cov;
    out[half_out + base0 + 2 * plane] = cov;
}

extern "C" void kernel_launch(void* const* d_in, const int* in_sizes, int n_in,
                              void* d_out, int out_size, void* d_ws, size_t ws_size,
                              hipStream_t stream) {
    const float* patch   = (const float*)d_in[0];
    const float* targets = (const float*)d_in[1];
    // d_in[2] = imgs — only used for shape in the reference; not read here.
    const float* angles  = (const float*)d_in[3];
    const float* seeds   = (const float*)d_in[4];
    float* out = (float*)d_out;

    const int tilesPerImg = (WW / TILE_W) * (HH / TILE_H);  // 1024
    dim3 grid(BB * tilesPerImg);                            // 16384 blocks
    dim3 block(256);
    PatchTransformer_43490838840065_kernel<<<grid, block, 0, stream>>>(
        patch, targets, angles, seeds, out);
}

// Round 3
// 136.370 us; speedup vs baseline: 1.0007x; 1.0007x over previous
//
#include <hip/hip_runtime.h>
#include <hip/hip_bf16.h>
#include <math.h>

// Problem constants (from setup_inputs): B=16, H=W=512, P=128, T=64
#define BB   16
#define HH   512
#define WW   512
#define PP   128
#define TT   64

#define TILE_W 64
#define TILE_H 16
// 256 threads/block, each thread owns 4 consecutive x pixels in one row.

__global__ __launch_bounds__(256)
void PatchTransformer_43490838840065_kernel(const float* __restrict__ patch,
                                            const float* __restrict__ targets,
                                            const float* __restrict__ angles,
                                            const float* __restrict__ seeds,
                                            float* __restrict__ out) {
    // ---- tile decode ----
    const int tilesX = WW / TILE_W;           // 8
    const int tilesY = HH / TILE_H;           // 32
    const int tilesPerImg = tilesX * tilesY;  // 256
    int bid = blockIdx.x;
    int img = bid / tilesPerImg;
    int tr  = bid % tilesPerImg;
    int ty  = tr / tilesX;
    int tx  = tr % tilesX;
    int x0t = tx * TILE_W;
    int y0t = ty * TILE_H;

    // ---- per-target params + tile culling ----
    __shared__ float s_cx[TT], s_cy[TT], s_c[TT], s_s[TT], s_scale[TT], s_add[TT];
    __shared__ int   s_list[TT];
    __shared__ int   s_cnt;

    int tid = threadIdx.x;
    if (tid == 0) s_cnt = 0;
    __syncthreads();

    if (tid < TT) {
        int   ib = (int)targets[tid * 6 + 0];
        float cx = targets[tid * 6 + 2] * (float)WW;
        float ps = targets[tid * 6 + 5] * (float)HH * 0.2f;   // RATIO_H
        float th = angles[tid] * 0.017453292519943295f;       // deg->rad
        float c  = cosf(th);
        float s  = sinf(th);
        float asum = fabsf(c) + fabsf(s);
        float ext  = ps * asum;                               // rotated bbox side
        float cy   = targets[tid * 6 + 3] * (float)HH - 0.2f * ext;
        float scale = (float)(PP - 1) / fmaxf(ps - 1.0f, 1.0f);
        s_cx[tid] = cx;  s_cy[tid] = cy;
        s_c[tid]  = c;   s_s[tid]  = s;
        s_scale[tid] = scale;
        s_add[tid]   = 0.1f * seeds[tid];                     // TEMP_FACTOR * seed

        // footprint: any-tap-in-bounds <=> px,py in [-1, P). In u/v space that's
        // |u|,|v| <= 65/scale. Axis-aligned bbox radius R = r*(|c|+|s|). +1 margin.
        float r = 65.0f / scale + 1.0f;
        float R = r * asum;
        bool hit = (ib == img) &&
                   (cx + R >= (float)x0t) && (cx - R <= (float)(x0t + TILE_W - 1)) &&
                   (cy + R >= (float)y0t) && (cy - R <= (float)(y0t + TILE_H - 1));
        if (hit) {
            int slot = atomicAdd(&s_cnt, 1);
            s_list[slot] = tid;
        }
    }
    __syncthreads();

    // ---- per-pixel accumulate: 4 consecutive x per thread ----
    int lx = (tid & 15) * 4;
    int ly = tid >> 4;
    int x  = x0t + lx;
    int y  = y0t + ly;
    float fyp = (float)y;

    float val[4] = {0.f, 0.f, 0.f, 0.f};
    float cov[4] = {0.f, 0.f, 0.f, 0.f};

    int n = s_cnt;
    for (int k = 0; k < n; ++k) {
        int t = s_list[k];
        float c  = s_c[t], s = s_s[t];
        float sc = s_scale[t];
        float add = s_add[t];
        float dy = fyp - s_cy[t];
        float dx0 = (float)x - s_cx[t];

        #pragma unroll
        for (int j = 0; j < 4; ++j) {
            float dx = dx0 + (float)j;
            float u  =  c * dx + s * dy;
            float v  = -s * dx + c * dy;
            float px = u * sc + 63.5f;   // half = (P-1)/2
            float py = v * sc + 63.5f;
            float fx0 = floorf(px), fy0 = floorf(py);
            int ix0 = (int)fx0, iy0 = (int)fy0;
            float wx = px - fx0, wy = py - fy0;

            #pragma unroll
            for (int dyy = 0; dyy <= 1; ++dyy) {
                #pragma unroll
                for (int dxx = 0; dxx <= 1; ++dxx) {
                    int iy = iy0 + dyy;
                    int ix = ix0 + dxx;
                    bool ok = (iy >= 0) & (iy < PP) & (ix >= 0) & (ix < PP);
                    float w = (dyy ? wy : 1.0f - wy) * (dxx ? wx : 1.0f - wx);
                    if (ok) {
                        float pv = patch[iy * PP + ix] + add;
                        pv = fminf(fmaxf(pv, 0.0f), 1.0f);    // clip(p0+temp,0,1)
                        val[j] += pv * w;
                        cov[j] += w;
                    }
                }
            }
        }
    }

    // ---- vectorized writes: val -> 3 planes of patch_tf, cov -> 3 planes of mask_tf ----
    size_t plane    = (size_t)HH * WW;
    size_t base0    = ((size_t)img * 3) * plane + (size_t)y * WW + x;
    size_t half_out = (size_t)BB * 3 * plane;
    float4 v4 = make_float4(val[0], val[1], val[2], val[3]);
    float4 c4 = make_float4(cov[0], cov[1], cov[2], cov[3]);
    *(float4*)(out + base0)                        = v4;
    *(float4*)(out + base0 + plane)                = v4;
    *(float4*)(out + base0 + 2 * plane)            = v4;
    *(float4*)(out + half_out + base0)             = c4;
    *(float4*)(out + half_out + base0 + plane)     = c4;
    *(float4*)(out + half_out + base0 + 2 * plane) = c4;
}

extern "C" void kernel_launch(void* const* d_in, const int* in_sizes, int n_in,
                              void* d_out, int out_size, void* d_ws, size_t ws_size,
                              hipStream_t stream) {
    const float* patch   = (const float*)d_in[0];
    const float* targets = (const float*)d_in[1];
    // d_in[2] = imgs — only used for shape in the reference; not read here.
    const float* angles  = (const float*)d_in[3];
    const float* seeds   = (const float*)d_in[4];
    float* out = (float*)d_out;

    const int tilesPerImg = (WW / TILE_W) * (HH / TILE_H);  // 256
    dim3 grid(BB * tilesPerImg);                            // 4096 blocks
    dim3 block(256);
    PatchTransformer_43490838840065_kernel<<<grid, block, 0, stream>>>(
        patch, targets, angles, seeds, out);
}